// Round 13
// baseline (101.148 us; speedup 1.0000x reference)
//
#include <hip/hip_runtime.h>
#include <cstdint>
#include <cstddef>

// Problem constants
#define BB 32
#define SS 512
#define HH 768
#define WW 256
#define LL 8
#define NINTENT 26
#define NSLOT 121

typedef float f32x4 __attribute__((ext_vector_type(4)));
typedef __bf16 bf16x8 __attribute__((ext_vector_type(8)));

static __device__ __forceinline__ float bf2f(unsigned short u) {
    union { unsigned int i; float f; } x; x.i = ((unsigned int)u) << 16; return x.f;
}
static __device__ __forceinline__ unsigned short f2bf(float f) {
    union { float f; unsigned int i; } x; x.f = f;
    unsigned int r = (x.i + 0x7fffu + ((x.i >> 16) & 1u)) >> 16;
    return (unsigned short)r;
}

// async global->LDS, 16B per lane, wave-uniform LDS base + lane*16
static __device__ __forceinline__ void gload16(const void* g, void* l) {
    __builtin_amdgcn_global_load_lds(
        (const __attribute__((address_space(1))) void*)g,
        (__attribute__((address_space(3))) void*)l, 16, 0, 0);
}

// read 8 f32, convert to 8 bf16, write one uint4 to LDS (per-lane reg staging)
static __device__ __forceinline__ void stage_f32_bf16(const float* g, uint4* dst) {
    float4 v0 = *reinterpret_cast<const float4*>(g);
    float4 v1 = *reinterpret_cast<const float4*>(g + 4);
    union { ushort4 h[2]; uint4 u; } pk;
    pk.h[0].x = f2bf(v0.x); pk.h[0].y = f2bf(v0.y);
    pk.h[0].z = f2bf(v0.z); pk.h[0].w = f2bf(v0.w);
    pk.h[1].x = f2bf(v1.x); pk.h[1].y = f2bf(v1.y);
    pk.h[1].z = f2bf(v1.z); pk.h[1].w = f2bf(v1.w);
    *dst = pk.u;
}

#define MF(a, b, c) __builtin_amdgcn_mfma_f32_16x16x32_bf16((a), (b), (c), 0, 0, 0)

// ================= K1: weight prep + accumulator zeroing =================
// [0,432):    64x64 transpose + hi/lo split (Wk,Wq) / hi (Wv); Wk also u-partials
// [432,816):  Wcomb left copy (bf16 Ws, zero pad) + wsbv partials
// [816,1392): zero Pacc; [1392,1488): zero WRacc
__global__ __launch_bounds__(256) void prep_w(
    const float* __restrict__ Wk, const float* __restrict__ Wq,
    const float* __restrict__ Wv, const float* __restrict__ Ws,
    const float* __restrict__ bq, const float* __restrict__ bv,
    unsigned short* __restrict__ WkT_hi, unsigned short* __restrict__ WkT_lo,
    unsigned short* __restrict__ WqT_hi, unsigned short* __restrict__ WqT_lo,
    unsigned short* __restrict__ WvT, unsigned short* __restrict__ Wcomb,
    float* __restrict__ u_part,     // [12][768]
    float* __restrict__ wsbv_part,  // [3][128]
    float* __restrict__ Pacc,       // [768][768] f32
    float* __restrict__ WRacc)      // [128][768] f32
{
    int bid = blockIdx.x;
    int t = threadIdx.x;

    if (bid < 432) {
        __shared__ float tl[64][65];
        int mb = bid / 144, tb = bid % 144;
        int tx = tb % 12, ty = tb / 12;
        const float* src = (mb == 0) ? Wk : (mb == 1) ? Wq : Wv;
        int rr = t >> 4, c4 = (t & 15) * 4;
#pragma unroll
        for (int j = 0; j < 4; j++) {
            float4 v = *reinterpret_cast<const float4*>(
                &src[(size_t)(ty * 64 + rr + 16 * j) * HH + tx * 64 + c4]);
            tl[rr + 16 * j][c4 + 0] = v.x; tl[rr + 16 * j][c4 + 1] = v.y;
            tl[rr + 16 * j][c4 + 2] = v.z; tl[rr + 16 * j][c4 + 3] = v.w;
        }
        __syncthreads();
        int il = t >> 4, o4 = (t & 15) * 4;
        unsigned short* dhi = (mb == 0) ? WkT_hi : (mb == 1) ? WqT_hi : WvT;
        unsigned short* dlo = (mb == 0) ? WkT_lo : WqT_lo;  // unused when mb==2
#pragma unroll
        for (int j = 0; j < 4; j++) {
            int i = il + 16 * j;
            float v0 = tl[o4 + 0][i], v1 = tl[o4 + 1][i];
            float v2 = tl[o4 + 2][i], v3 = tl[o4 + 3][i];
            size_t off = (size_t)(tx * 64 + i) * HH + ty * 64 + o4;
            ushort4 h;
            h.x = f2bf(v0); h.y = f2bf(v1); h.z = f2bf(v2); h.w = f2bf(v3);
            *reinterpret_cast<ushort4*>(&dhi[off]) = h;
            if (mb < 2) {
                ushort4 l;
                l.x = f2bf(v0 - bf2f(h.x)); l.y = f2bf(v1 - bf2f(h.y));
                l.z = f2bf(v2 - bf2f(h.z)); l.w = f2bf(v3 - bf2f(h.w));
                *reinterpret_cast<ushort4*>(&dlo[off]) = l;
            }
        }
        if (mb == 0) {
            int c = t >> 2, q = t & 3;
            float s = 0.f;
#pragma unroll
            for (int r = 0; r < 16; r++)
                s += bq[ty * 64 + q * 16 + r] * tl[q * 16 + r][c];
            s += __shfl_xor(s, 1);
            s += __shfl_xor(s, 2);
            if (q == 0) u_part[ty * HH + tx * 64 + c] = s;
        }
    } else if (bid < 816) {
        __shared__ float wred[4];
        int bid2 = bid - 432;
        int idx = bid2 * 256 + t;         // 0..98303 over 128x768
        int row = idx / HH, col = idx % HH;
        float v = (row < NSLOT) ? Ws[row * HH + col] : 0.f;
        Wcomb[row * 1536 + col] = f2bf(v);
        float pv = v * bv[col];
        int lane = t & 63, wave = t >> 6;
#pragma unroll
        for (int off = 32; off > 0; off >>= 1) pv += __shfl_xor(pv, off);
        if (lane == 0) wred[wave] = pv;
        __syncthreads();
        if (t == 0)
            wsbv_part[(bid2 % 3) * 128 + row] = wred[0] + wred[1] + wred[2] + wred[3];
    } else {
        float4 z = {0.f, 0.f, 0.f, 0.f};
        int zb = bid - 816;
        if (zb < 576) ((float4*)Pacc)[zb * 256 + t] = z;
        else          ((float4*)WRacc)[(zb - 576) * 256 + t] = z;
    }
}

// ================= K2: weight GEMMs (atomic acc) + gather + res_id + sums ===
// [0,288):    G1: atomicAdd hi.hi + lo.hi + hi.lo k-slice into Pacc
// [288,336):  G2: atomicAdd Ws.WvT^T k-slice into WRacc
// [336,2384): gather first rows -> slotA left half
// [2384,2592): res_id, one wave per (bb, o)
// [2592,2595): u = sum u_part; 2595: wsbv
__global__ __launch_bounds__(256) void gemm_weights(
    const uint4* __restrict__ WkT_hi, const uint4* __restrict__ WkT_lo,
    const uint4* __restrict__ WqT_hi, const uint4* __restrict__ WqT_lo,
    const uint4* __restrict__ WvT, const uint4* __restrict__ Wcomb,
    const float* __restrict__ res_all, const int* __restrict__ starts,
    const float* __restrict__ res, const float* __restrict__ id_w,
    const float* __restrict__ id_b,
    const float* __restrict__ u_part, const float* __restrict__ wsbv_part,
    float* __restrict__ Pacc,    // [768][768]
    float* __restrict__ WRacc,   // [128][768]
    float* __restrict__ u, float* __restrict__ wsbv,
    unsigned short* __restrict__ slotA,  // [8192][1536]
    float* __restrict__ out)
{
    __shared__ uint4 sA[512];
    __shared__ uint4 sB[512];
    int bid = blockIdx.x;
    int t = threadIdx.x;
    int lane = t & 63, wave = t >> 6;

    if (bid >= 2592) {           // ---- u / wsbv sums ----
        if (bid < 2595) {
            int c = (bid - 2592) * 256 + t;
            float s = 0.f;
#pragma unroll
            for (int ty = 0; ty < 12; ty++) s += u_part[ty * HH + c];
            u[c] = s;
        } else if (t < 128) {
            wsbv[t] = wsbv_part[t] + wsbv_part[128 + t] + wsbv_part[256 + t];
        }
        return;
    }
    if (bid >= 2384) {           // ---- res_id: wave per (bb, o) ----
        int w = (bid - 2384) * 4 + wave;   // 0..831
        int bb = w / 26, o = w - bb * 26;
        const float* rrow = res + bb * HH + lane * 12;
        const float* wrow = id_w + o * HH + lane * 12;
        float s = 0.f;
#pragma unroll
        for (int c = 0; c < 3; c++) {
            float4 a = *reinterpret_cast<const float4*>(&rrow[c * 4]);
            float4 b = *reinterpret_cast<const float4*>(&wrow[c * 4]);
            s += a.x * b.x + a.y * b.y + a.z * b.z + a.w * b.w;
        }
#pragma unroll
        for (int off = 32; off > 0; off >>= 1) s += __shfl_xor(s, off);
        if (lane == 0) out[bb * NINTENT + o] = s + id_b[o];
        return;
    }
    if (bid >= 336) {            // ---- gather first rows ----
        int gw = (bid - 336) * 4 + wave;
        int b = gw >> 8;
        int s0 = starts[gw];
        const float* src = res_all + (size_t)(b * SS + s0) * HH + lane * 12;
        unsigned short* dst = slotA + (size_t)gw * 1536 + lane * 12;
#pragma unroll
        for (int c2 = 0; c2 < 3; c2++) {
            float4 v = *reinterpret_cast<const float4*>(&src[c2 * 4]);
            ushort4 o;
            o.x = f2bf(v.x); o.y = f2bf(v.y); o.z = f2bf(v.z); o.w = f2bf(v.w);
            *reinterpret_cast<ushort4*>(&dst[c2 * 4]) = o;
        }
        return;
    }

    int wm = wave >> 1, wn = wave & 1;
    int l16 = lane & 15, lk = lane >> 4;
    int srow = lane >> 2, schk = lane & 3;
    uint4* sA0 = &sA[wave * 128];
    uint4* sA1 = &sA[wave * 128 + 64];
    uint4* sB0 = &sB[wave * 128];
    uint4* sB1 = &sB[wave * 128 + 64];

    f32x4 acc[4][4] = {};

    if (bid < 288) {
        int tile = bid >> 3, ks = bid & 7;
        int mt = tile / 6, nt = tile % 6;
        int kb = ks * 12;
#pragma unroll
        for (int p = 0; p < 3; p++) {
            const uint4* Ab = (p == 1) ? WkT_lo : WkT_hi;
            const uint4* Bb = (p == 2) ? WqT_lo : WqT_hi;
            const uint4* Ag0 = Ab + (size_t)(mt * 128 + wave * 32 + srow) * 96 + kb + schk;
            const uint4* Ag1 = Ag0 + (size_t)16 * 96;
            const uint4* Bg0 = Bb + (size_t)(nt * 128 + wave * 32 + srow) * 96 + kb + schk;
            const uint4* Bg1 = Bg0 + (size_t)16 * 96;
            for (int k0 = 0; k0 < 12; k0 += 4) {
                gload16(Ag0 + k0, sA0); gload16(Ag1 + k0, sA1);
                gload16(Bg0 + k0, sB0); gload16(Bg1 + k0, sB1);
                __syncthreads();
                bf16x8 af[4], bfr[4];
#pragma unroll
                for (int i = 0; i < 4; i++)
                    af[i] = *reinterpret_cast<const bf16x8*>(&sA[(wm * 64 + i * 16 + l16) * 4 + lk]);
#pragma unroll
                for (int j = 0; j < 4; j++)
                    bfr[j] = *reinterpret_cast<const bf16x8*>(&sB[(wn * 64 + j * 16 + l16) * 4 + lk]);
#pragma unroll
                for (int i = 0; i < 4; i++)
#pragma unroll
                    for (int j = 0; j < 4; j++)
                        acc[i][j] = MF(af[i], bfr[j], acc[i][j]);
                __syncthreads();
            }
        }
#pragma unroll
        for (int i = 0; i < 4; i++)
#pragma unroll
            for (int j = 0; j < 4; j++) {
                int col = nt * 128 + wn * 64 + j * 16 + l16;
#pragma unroll
                for (int q = 0; q < 4; q++) {
                    int row = mt * 128 + wm * 64 + i * 16 + lk * 4 + q;
                    atomicAdd(&Pacc[(size_t)row * HH + col], acc[i][j][q]);
                }
            }
    } else {
        int idx = bid - 288;
        int nt = idx >> 3, ks = idx & 7;
        int kb = ks * 12;
        const uint4* Ag0 = Wcomb + (size_t)(wave * 32 + srow) * 192 + kb + schk;
        const uint4* Ag1 = Ag0 + (size_t)16 * 192;
        const uint4* Bg0 = WvT + (size_t)(nt * 128 + wave * 32 + srow) * 96 + kb + schk;
        const uint4* Bg1 = Bg0 + (size_t)16 * 96;
        for (int k0 = 0; k0 < 12; k0 += 4) {
            gload16(Ag0 + k0, sA0); gload16(Ag1 + k0, sA1);
            gload16(Bg0 + k0, sB0); gload16(Bg1 + k0, sB1);
            __syncthreads();
            bf16x8 af[4], bfr[4];
#pragma unroll
            for (int i = 0; i < 4; i++)
                af[i] = *reinterpret_cast<const bf16x8*>(&sA[(wm * 64 + i * 16 + l16) * 4 + lk]);
#pragma unroll
            for (int j = 0; j < 4; j++)
                bfr[j] = *reinterpret_cast<const bf16x8*>(&sB[(wn * 64 + j * 16 + l16) * 4 + lk]);
#pragma unroll
            for (int i = 0; i < 4; i++)
#pragma unroll
                for (int j = 0; j < 4; j++)
                    acc[i][j] = MF(af[i], bfr[j], acc[i][j]);
            __syncthreads();
        }
#pragma unroll
        for (int i = 0; i < 4; i++)
#pragma unroll
            for (int j = 0; j < 4; j++) {
                int col = nt * 128 + wn * 64 + j * 16 + l16;
#pragma unroll
                for (int q = 0; q < 4; q++) {
                    int row = wm * 64 + i * 16 + lk * 4 + q;
                    atomicAdd(&WRacc[(size_t)row * HH + col], acc[i][j][q]);
                }
            }
    }
}

// ================= K4': qp GEMM (768, B from Pacc f32) + slot-left (256) =====
__global__ __launch_bounds__(256) void gemm_qp_sl(
    const uint4* __restrict__ A,     // slotA [8192][192]
    const float* __restrict__ Pacc,  // [768][768] f32
    const uint4* __restrict__ Wc,    // Wcomb [128][192]
    const float* __restrict__ u,
    unsigned short* __restrict__ qp, // [8192][768] bf16
    float* __restrict__ Cpart0)      // [8192][128]
{
    __shared__ uint4 sA[256];
    __shared__ uint4 sB[512];

    int bid = blockIdx.x;
    int t = threadIdx.x;
    int lane = t & 63, wave = t >> 6;
    int wm = wave >> 1, wn = wave & 1;
    int l16 = lane & 15, lk = lane >> 4;
    int srow = lane >> 2, schk = lane & 3;

    if (bid >= 768) {            // ---- slot-left: 32x128 tile (bf16 B) ----
        int mt = bid - 768;      // 0..255
        const uint4* Ag  = A + (size_t)(mt * 32 + wave * 16 + srow) * 192 + schk;
        const uint4* Bg0 = Wc + (size_t)(wave * 32 + srow) * 192 + schk;
        const uint4* Bg1 = Bg0 + (size_t)16 * 192;
        uint4* sB0 = &sB[wave * 128];
        uint4* sB1 = &sB[wave * 128 + 64];

        f32x4 acc[4] = {};
        for (int k0 = 0; k0 < 96; k0 += 4) {
            if (wave < 2) gload16(Ag + k0, &sA[wave * 64]);
            gload16(Bg0 + k0, sB0);
            gload16(Bg1 + k0, sB1);
            __syncthreads();
            bf16x8 af = *reinterpret_cast<const bf16x8*>(&sA[(wm * 16 + l16) * 4 + lk]);
            bf16x8 bfr[4];
#pragma unroll
            for (int j = 0; j < 4; j++)
                bfr[j] = *reinterpret_cast<const bf16x8*>(&sB[(wn * 64 + j * 16 + l16) * 4 + lk]);
#pragma unroll
            for (int j = 0; j < 4; j++)
                acc[j] = MF(af, bfr[j], acc[j]);
            __syncthreads();
        }
#pragma unroll
        for (int j = 0; j < 4; j++) {
            int col = wn * 64 + j * 16 + l16;
#pragma unroll
            for (int q = 0; q < 4; q++) {
                int row = mt * 32 + wm * 16 + lk * 4 + q;
                Cpart0[(size_t)row * 128 + col] = acc[j][q];
            }
        }
        return;
    }

    // ---- qp: 64x128 tile, XCD swizzle; B reg-staged f32->bf16 from Pacc ----
    bid = (bid & 7) * 96 + (bid >> 3);
    int mt = bid / 6, nt = bid % 6;

    const uint4* Ag = A + (size_t)(mt * 64 + wave * 16 + srow) * 192 + schk;
    const float* Bf0 = Pacc + (size_t)(nt * 128 + wave * 32 + srow) * HH + schk * 8;
    const float* Bf1 = Bf0 + (size_t)16 * HH;
    uint4* sAp = &sA[wave * 64];
    uint4* sB0 = &sB[wave * 128];
    uint4* sB1 = &sB[wave * 128 + 64];

    f32x4 acc[2][4] = {};

    for (int k0 = 0; k0 < 96; k0 += 4) {
        gload16(Ag + k0, sAp);
        stage_f32_bf16(Bf0 + (size_t)k0 * 8, &sB0[lane]);
        stage_f32_bf16(Bf1 + (size_t)k0 * 8, &sB1[lane]);
        __syncthreads();
        bf16x8 af[2], bfr[4];
#pragma unroll
        for (int i = 0; i < 2; i++)
            af[i] = *reinterpret_cast<const bf16x8*>(&sA[(wm * 32 + i * 16 + l16) * 4 + lk]);
#pragma unroll
        for (int j = 0; j < 4; j++)
            bfr[j] = *reinterpret_cast<const bf16x8*>(&sB[(wn * 64 + j * 16 + l16) * 4 + lk]);
#pragma unroll
        for (int i = 0; i < 2; i++)
#pragma unroll
            for (int j = 0; j < 4; j++)
                acc[i][j] = MF(af[i], bfr[j], acc[i][j]);
        __syncthreads();
    }

#pragma unroll
    for (int i = 0; i < 2; i++)
#pragma unroll
        for (int j = 0; j < 4; j++) {
            int col = nt * 128 + wn * 64 + j * 16 + l16;
            float add = u[col];
#pragma unroll
            for (int q = 0; q < 4; q++) {
                int row = mt * 64 + wm * 32 + i * 16 + lk * 4 + q;
                qp[(size_t)row * HH + col] = f2bf(acc[i][j][q] + add);
            }
        }
}

// ================= K5: flash attention (bf16 qp, online softmax) ============
__global__ __launch_bounds__(256) void attn2_kernel(
    const unsigned short* __restrict__ qp,  // [8192][768] bf16
    const float* __restrict__ res_all,      // [B*S][768] f32
    const int* __restrict__ starts,
    const int* __restrict__ lens,
    unsigned short* __restrict__ slotA)     // [8192][1536], writes cols 768..1535
{
    int bid = blockIdx.x;
    bid = (bid & 7) * 256 + (bid >> 3);              // 2048 = 8 x 256
    int gw = bid * 4 + (threadIdx.x >> 6);
    int lane = threadIdx.x & 63;
    int b = gw >> 8;
    int s0 = starts[gw];
    int sl = lens[gw];                               // 1..7, wave-uniform

    unsigned short* dst = slotA + (size_t)gw * 1536 + 768 + lane * 12;

    if (sl == 1) {                                   // word = first; xbar half = 0
        ushort4 z = {0, 0, 0, 0};
#pragma unroll
        for (int c = 0; c < 3; c++) *reinterpret_cast<ushort4*>(&dst[c * 4]) = z;
        return;
    }

    const unsigned short* qrow = qp + (size_t)gw * HH + lane * 12;
    float q[12];
#pragma unroll
    for (int c = 0; c < 3; c++) {
        ushort4 v = *reinterpret_cast<const ushort4*>(&qrow[c * 4]);
        q[c * 4 + 0] = bf2f(v.x); q[c * 4 + 1] = bf2f(v.y);
        q[c * 4 + 2] = bf2f(v.z); q[c * 4 + 3] = bf2f(v.w);
    }

    float m = -1e30f, ssum = 0.f;
    float acc[12];
#pragma unroll
    for (int i = 0; i < 12; i++) acc[i] = 0.f;

    for (int k = 0; k < LL; k++) {
        if (k > sl) break;                           // uniform branch
        int s = s0 + k; if (s > SS - 1) s = SS - 1;
        const float* xr = res_all + (size_t)(b * SS + s) * HH + lane * 12;
        float x[12];
        float partial = 0.f;
#pragma unroll
        for (int c = 0; c < 3; c++) {
            float4 v = *reinterpret_cast<const float4*>(&xr[c * 4]);
            x[c * 4 + 0] = v.x; x[c * 4 + 1] = v.y;
            x[c * 4 + 2] = v.z; x[c * 4 + 3] = v.w;
            partial += q[c * 4 + 0] * v.x + q[c * 4 + 1] * v.y
                     + q[c * 4 + 2] * v.z + q[c * 4 + 3] * v.w;
        }
#pragma unroll
        for (int off = 32; off > 0; off >>= 1) partial += __shfl_xor(partial, off);

        float mnew = (partial > m) ? partial : m;
        float scale = __expf(m - mnew);
        float e = __expf(partial - mnew);
        ssum = ssum * scale + e;
#pragma unroll
        for (int i = 0; i < 12; i++) acc[i] = acc[i] * scale + e * x[i];
        m = mnew;
    }

    float inv = 1.f / ssum;
#pragma unroll
    for (int c = 0; c < 3; c++) {
        ushort4 o;
        o.x = f2bf(acc[c * 4 + 0] * inv); o.y = f2bf(acc[c * 4 + 1] * inv);
        o.z = f2bf(acc[c * 4 + 2] * inv); o.w = f2bf(acc[c * 4 + 3] * inv);
        *reinterpret_cast<ushort4*>(&dst[c * 4]) = o;
    }
}

// ================= K6: slot-right GEMM (B from WRacc f32) + merge ===========
__global__ __launch_bounds__(256) void gemm_slot_r(
    const uint4* __restrict__ A,     // slotA [8192][192]
    const float* __restrict__ WRacc, // [128][768] f32
    const float* __restrict__ Cpart0,
    const float* __restrict__ bias, const float* __restrict__ wsbv,
    const int* __restrict__ lens,
    float* __restrict__ outsf)       // [8192][121]
{
    __shared__ uint4 sA[128];   // 32 rows
    __shared__ uint4 sB[512];   // 128 rows

    int mt = blockIdx.x;
    int t = threadIdx.x;
    int lane = t & 63, wave = t >> 6;
    int wm = wave >> 1, wn = wave & 1;
    int l16 = lane & 15, lk = lane >> 4;
    int srow = lane >> 2, schk = lane & 3;

    const uint4* Ag = A + (size_t)(mt * 32 + wave * 16 + srow) * 192 + 96 + schk;
    const float* Bf0 = WRacc + (size_t)(wave * 32 + srow) * HH + schk * 8;
    const float* Bf1 = Bf0 + (size_t)16 * HH;
    uint4* sB0 = &sB[wave * 128];
    uint4* sB1 = &sB[wave * 128 + 64];

    f32x4 acc[4] = {};

    for (int k0 = 0; k0 < 96; k0 += 4) {
        if (wave < 2) gload16(Ag + k0, &sA[wave * 64]);
        stage_f32_bf16(Bf0 + (size_t)k0 * 8, &sB0[lane]);
        stage_f32_bf16(Bf1 + (size_t)k0 * 8, &sB1[lane]);
        __syncthreads();
        bf16x8 af = *reinterpret_cast<const bf16x8*>(&sA[(wm * 16 + l16) * 4 + lk]);
        bf16x8 bfr[4];
#pragma unroll
        for (int j = 0; j < 4; j++)
            bfr[j] = *reinterpret_cast<const bf16x8*>(&sB[(wn * 64 + j * 16 + l16) * 4 + lk]);
#pragma unroll
        for (int j = 0; j < 4; j++)
            acc[j] = MF(af, bfr[j], acc[j]);
        __syncthreads();
    }

#pragma unroll
    for (int j = 0; j < 4; j++) {
        int col = wn * 64 + j * 16 + l16;
        if (col < NSLOT) {
            float bc = bias[col], wv = wsbv[col];
#pragma unroll
            for (int q = 0; q < 4; q++) {
                int row = mt * 32 + wm * 16 + lk * 4 + q;
                float v = acc[j][q] + Cpart0[(size_t)row * 128 + col]
                        + bc + ((lens[row] > 1) ? wv : 0.f);
                outsf[(size_t)row * NSLOT + col] = v;
            }
        }
    }
}

// ---------------- launch ----------------
extern "C" void kernel_launch(void* const* d_in, const int* in_sizes, int n_in,
                              void* d_out, int out_size, void* d_ws, size_t ws_size,
                              hipStream_t stream) {
    const float* res_all    = (const float*)d_in[0];
    const float* res        = (const float*)d_in[1];
    const int*   starts     = (const int*)d_in[2];
    const int*   lens       = (const int*)d_in[3];
    const float* Wsq_w      = (const float*)d_in[4];
    const float* Wsq_b      = (const float*)d_in[5];
    const float* Wsk_w      = (const float*)d_in[6];
    const float* Wsk_b      = (const float*)d_in[7];
    const float* Wsv_w      = (const float*)d_in[8];
    const float* Wsv_b      = (const float*)d_in[9];
    const float* lin_id_w   = (const float*)d_in[10];
    const float* lin_id_b   = (const float*)d_in[11];
    const float* lin_slot_w = (const float*)d_in[12];
    const float* lin_slot_b = (const float*)d_in[13];
    float* out = (float*)d_out;
    (void)Wsk_b;  // softmax-invariant (constant over k)

    char* ws = (char*)d_ws;
    unsigned short* slotA     = (unsigned short*)(ws + 0);          // 8192x1536 bf16
    unsigned short* qp        = (unsigned short*)(ws + 25165824);   // 8192x768 bf16
    unsigned short* WkT_hi    = (unsigned short*)(ws + 50331648);
    unsigned short* WkT_lo    = (unsigned short*)(ws + 51511296);
    unsigned short* WqT_hi    = (unsigned short*)(ws + 52690944);
    unsigned short* WqT_lo    = (unsigned short*)(ws + 53870592);
    unsigned short* WvT       = (unsigned short*)(ws + 55050240);
    unsigned short* Wcomb     = (unsigned short*)(ws + 57409536);   // 128x1536 bf16
    float*          u         = (float*)(ws + 57802752);            // 768
    float*          wsbv      = (float*)(ws + 57805824);            // 128
    float*          u_part    = (float*)(ws + 57806336);            // 12x768
    float*          wsbv_part = (float*)(ws + 57843200);            // 3x128
    float*          Pacc      = (float*)(ws + 57845760);            // 768x768 f32
    float*          WRacc     = (float*)(ws + 60205056);            // 128x768 f32
    float*          Cpart0    = (float*)(ws + 60598272);            // 8192x128 f32

    // K1: weight prep + zero accumulators
    prep_w<<<1488, 256, 0, stream>>>(
        Wsk_w, Wsq_w, Wsv_w, lin_slot_w, Wsq_b, Wsv_b,
        WkT_hi, WkT_lo, WqT_hi, WqT_lo, WvT, Wcomb,
        u_part, wsbv_part, Pacc, WRacc);

    // K2: weight GEMMs (atomic acc) + gather + res_id + u/wsbv sums
    gemm_weights<<<2596, 256, 0, stream>>>(
        (const uint4*)WkT_hi, (const uint4*)WkT_lo,
        (const uint4*)WqT_hi, (const uint4*)WqT_lo,
        (const uint4*)WvT, (const uint4*)Wcomb,
        res_all, starts, res, lin_id_w, lin_id_b,
        u_part, wsbv_part, Pacc, WRacc, u, wsbv, slotA, out);

    // K4': qp GEMM (bf16 out, B from Pacc) + slot-left GEMM
    gemm_qp_sl<<<1024, 256, 0, stream>>>((const uint4*)slotA, Pacc,
                                         (const uint4*)Wcomb, u, qp, Cpart0);

    // K5: flash attention -> slotA right half
    attn2_kernel<<<2048, 256, 0, stream>>>(qp, res_all, starts, lens, slotA);

    // K6: slot-right GEMM (B from WRacc) + merge -> out
    gemm_slot_r<<<256, 256, 0, stream>>>((const uint4*)slotA, WRacc,
                                         Cpart0, lin_slot_b, wsbv, lens, out + 832);
}

// Round 14
// 84.400 us; speedup vs baseline: 1.1984x; 1.1984x over previous
//
#include <hip/hip_runtime.h>
#include <cstdint>
#include <cstddef>

// Problem constants
#define BB 32
#define SS 512
#define HH 768
#define WW 256
#define LL 8
#define NINTENT 26
#define NSLOT 121

typedef float f32x4 __attribute__((ext_vector_type(4)));
typedef __bf16 bf16x8 __attribute__((ext_vector_type(8)));

static __device__ __forceinline__ float bf2f(unsigned short u) {
    union { unsigned int i; float f; } x; x.i = ((unsigned int)u) << 16; return x.f;
}
static __device__ __forceinline__ unsigned short f2bf(float f) {
    union { float f; unsigned int i; } x; x.f = f;
    unsigned int r = (x.i + 0x7fffu + ((x.i >> 16) & 1u)) >> 16;
    return (unsigned short)r;
}

// async global->LDS, 16B per lane, wave-uniform LDS base + lane*16
static __device__ __forceinline__ void gload16(const void* g, void* l) {
    __builtin_amdgcn_global_load_lds(
        (const __attribute__((address_space(1))) void*)g,
        (__attribute__((address_space(3))) void*)l, 16, 0, 0);
}

#define MF(a, b, c) __builtin_amdgcn_mfma_f32_16x16x32_bf16((a), (b), (c), 0, 0, 0)

// ================= K1: weight prep =================
// [0,432):   64x64 transpose + hi/lo split (Wk,Wq) / hi (Wv); Wk also u-partials
// [432,816): Wcomb left copy (bf16 Ws, zero pad) + wsbv partials
__global__ __launch_bounds__(256) void prep_w(
    const float* __restrict__ Wk, const float* __restrict__ Wq,
    const float* __restrict__ Wv, const float* __restrict__ Ws,
    const float* __restrict__ bq, const float* __restrict__ bv,
    unsigned short* __restrict__ WkT_hi, unsigned short* __restrict__ WkT_lo,
    unsigned short* __restrict__ WqT_hi, unsigned short* __restrict__ WqT_lo,
    unsigned short* __restrict__ WvT, unsigned short* __restrict__ Wcomb,
    float* __restrict__ u_part,     // [12][768]
    float* __restrict__ wsbv_part)  // [3][128]
{
    int bid = blockIdx.x;
    int t = threadIdx.x;

    if (bid < 432) {
        __shared__ float tl[64][65];
        int mb = bid / 144, tb = bid % 144;
        int tx = tb % 12, ty = tb / 12;
        const float* src = (mb == 0) ? Wk : (mb == 1) ? Wq : Wv;
        int rr = t >> 4, c4 = (t & 15) * 4;
#pragma unroll
        for (int j = 0; j < 4; j++) {
            float4 v = *reinterpret_cast<const float4*>(
                &src[(size_t)(ty * 64 + rr + 16 * j) * HH + tx * 64 + c4]);
            tl[rr + 16 * j][c4 + 0] = v.x; tl[rr + 16 * j][c4 + 1] = v.y;
            tl[rr + 16 * j][c4 + 2] = v.z; tl[rr + 16 * j][c4 + 3] = v.w;
        }
        __syncthreads();
        int il = t >> 4, o4 = (t & 15) * 4;
        unsigned short* dhi = (mb == 0) ? WkT_hi : (mb == 1) ? WqT_hi : WvT;
        unsigned short* dlo = (mb == 0) ? WkT_lo : WqT_lo;  // unused when mb==2
#pragma unroll
        for (int j = 0; j < 4; j++) {
            int i = il + 16 * j;
            float v0 = tl[o4 + 0][i], v1 = tl[o4 + 1][i];
            float v2 = tl[o4 + 2][i], v3 = tl[o4 + 3][i];
            size_t off = (size_t)(tx * 64 + i) * HH + ty * 64 + o4;
            ushort4 h;
            h.x = f2bf(v0); h.y = f2bf(v1); h.z = f2bf(v2); h.w = f2bf(v3);
            *reinterpret_cast<ushort4*>(&dhi[off]) = h;
            if (mb < 2) {
                ushort4 l;
                l.x = f2bf(v0 - bf2f(h.x)); l.y = f2bf(v1 - bf2f(h.y));
                l.z = f2bf(v2 - bf2f(h.z)); l.w = f2bf(v3 - bf2f(h.w));
                *reinterpret_cast<ushort4*>(&dlo[off]) = l;
            }
        }
        if (mb == 0) {
            int c = t >> 2, q = t & 3;
            float s = 0.f;
#pragma unroll
            for (int r = 0; r < 16; r++)
                s += bq[ty * 64 + q * 16 + r] * tl[q * 16 + r][c];
            s += __shfl_xor(s, 1);
            s += __shfl_xor(s, 2);
            if (q == 0) u_part[ty * HH + tx * 64 + c] = s;
        }
    } else {
        __shared__ float wred[4];
        int bid2 = bid - 432;
        int idx = bid2 * 256 + t;         // 0..98303 over 128x768
        int row = idx / HH, col = idx % HH;
        float v = (row < NSLOT) ? Ws[row * HH + col] : 0.f;
        Wcomb[row * 1536 + col] = f2bf(v);
        float pv = v * bv[col];
        int lane = t & 63, wave = t >> 6;
#pragma unroll
        for (int off = 32; off > 0; off >>= 1) pv += __shfl_xor(pv, off);
        if (lane == 0) wred[wave] = pv;
        __syncthreads();
        if (t == 0)
            wsbv_part[(bid2 % 3) * 128 + row] = wred[0] + wred[1] + wred[2] + wred[3];
    }
}

// ================= K2: weight GEMMs (128x128, K-split x8) + gather + res_id =
// [0,288):    G1: Ppart[ks] = hi.hi + lo.hi + hi.lo (4-buffer staging)
// [288,336):  G2: WRpart[ks] = Ws . WvT^T over k-slice
// [336,2384): gather first rows -> slotA left half
// [2384,2592): res_id, one wave per (bb, o)
__global__ __launch_bounds__(256) void gemm_weights(
    const uint4* __restrict__ WkT_hi, const uint4* __restrict__ WkT_lo,
    const uint4* __restrict__ WqT_hi, const uint4* __restrict__ WqT_lo,
    const uint4* __restrict__ WvT, const uint4* __restrict__ Wcomb,
    const float* __restrict__ res_all, const int* __restrict__ starts,
    const float* __restrict__ res, const float* __restrict__ id_w,
    const float* __restrict__ id_b,
    float* __restrict__ Ppart,   // [8][768][768]
    float* __restrict__ WRpart,  // [8][128][768]
    unsigned short* __restrict__ slotA,  // [8192][1536]
    float* __restrict__ out)
{
    __shared__ uint4 sAh[512];
    __shared__ uint4 sAl[512];
    __shared__ uint4 sBh[512];
    __shared__ uint4 sBl[512];
    int bid = blockIdx.x;
    int t = threadIdx.x;
    int lane = t & 63, wave = t >> 6;

    if (bid >= 2384) {           // ---- res_id: wave per (bb, o) ----
        int w = (bid - 2384) * 4 + wave;   // 0..831
        int bb = w / 26, o = w - bb * 26;
        const float* rrow = res + bb * HH + lane * 12;
        const float* wrow = id_w + o * HH + lane * 12;
        float s = 0.f;
#pragma unroll
        for (int c = 0; c < 3; c++) {
            float4 a = *reinterpret_cast<const float4*>(&rrow[c * 4]);
            float4 b = *reinterpret_cast<const float4*>(&wrow[c * 4]);
            s += a.x * b.x + a.y * b.y + a.z * b.z + a.w * b.w;
        }
#pragma unroll
        for (int off = 32; off > 0; off >>= 1) s += __shfl_xor(s, off);
        if (lane == 0) out[bb * NINTENT + o] = s + id_b[o];
        return;
    }
    if (bid >= 336) {            // ---- gather first rows ----
        int gw = (bid - 336) * 4 + wave;
        int b = gw >> 8;
        int s0 = starts[gw];
        const float* src = res_all + (size_t)(b * SS + s0) * HH + lane * 12;
        unsigned short* dst = slotA + (size_t)gw * 1536 + lane * 12;
#pragma unroll
        for (int c2 = 0; c2 < 3; c2++) {
            float4 v = *reinterpret_cast<const float4*>(&src[c2 * 4]);
            ushort4 o;
            o.x = f2bf(v.x); o.y = f2bf(v.y); o.z = f2bf(v.z); o.w = f2bf(v.w);
            *reinterpret_cast<ushort4*>(&dst[c2 * 4]) = o;
        }
        return;
    }

    int wm = wave >> 1, wn = wave & 1;
    int l16 = lane & 15, lk = lane >> 4;
    int srow = lane >> 2, schk = lane & 3;

    f32x4 acc[4][4] = {};

    if (bid < 288) {
        int tile = bid >> 3, ks = bid & 7;
        int mt = tile / 6, nt = tile % 6;
        int kb = ks * 12;
        size_t aoff = (size_t)(mt * 128 + wave * 32 + srow) * 96 + kb + schk;
        size_t boff = (size_t)(nt * 128 + wave * 32 + srow) * 96 + kb + schk;
        const uint4* Ah0 = WkT_hi + aoff; const uint4* Ah1 = Ah0 + (size_t)16 * 96;
        const uint4* Al0 = WkT_lo + aoff; const uint4* Al1 = Al0 + (size_t)16 * 96;
        const uint4* Bh0 = WqT_hi + boff; const uint4* Bh1 = Bh0 + (size_t)16 * 96;
        const uint4* Bl0 = WqT_lo + boff; const uint4* Bl1 = Bl0 + (size_t)16 * 96;
        uint4* dAh0 = &sAh[wave * 128]; uint4* dAh1 = dAh0 + 64;
        uint4* dAl0 = &sAl[wave * 128]; uint4* dAl1 = dAl0 + 64;
        uint4* dBh0 = &sBh[wave * 128]; uint4* dBh1 = dBh0 + 64;
        uint4* dBl0 = &sBl[wave * 128]; uint4* dBl1 = dBl0 + 64;

        for (int k0 = 0; k0 < 12; k0 += 4) {
            gload16(Ah0 + k0, dAh0); gload16(Ah1 + k0, dAh1);
            gload16(Al0 + k0, dAl0); gload16(Al1 + k0, dAl1);
            gload16(Bh0 + k0, dBh0); gload16(Bh1 + k0, dBh1);
            gload16(Bl0 + k0, dBl0); gload16(Bl1 + k0, dBl1);
            __syncthreads();
            bf16x8 afh[4], afl[4], bfh[4], bfl[4];
#pragma unroll
            for (int i = 0; i < 4; i++) {
                int ro = (wm * 64 + i * 16 + l16) * 4 + lk;
                afh[i] = *reinterpret_cast<const bf16x8*>(&sAh[ro]);
                afl[i] = *reinterpret_cast<const bf16x8*>(&sAl[ro]);
            }
#pragma unroll
            for (int j = 0; j < 4; j++) {
                int ro = (wn * 64 + j * 16 + l16) * 4 + lk;
                bfh[j] = *reinterpret_cast<const bf16x8*>(&sBh[ro]);
                bfl[j] = *reinterpret_cast<const bf16x8*>(&sBl[ro]);
            }
#pragma unroll
            for (int i = 0; i < 4; i++)
#pragma unroll
                for (int j = 0; j < 4; j++)
                    acc[i][j] = MF(afh[i], bfh[j], acc[i][j]);
#pragma unroll
            for (int i = 0; i < 4; i++)
#pragma unroll
                for (int j = 0; j < 4; j++)
                    acc[i][j] = MF(afl[i], bfh[j], acc[i][j]);
#pragma unroll
            for (int i = 0; i < 4; i++)
#pragma unroll
                for (int j = 0; j < 4; j++)
                    acc[i][j] = MF(afh[i], bfl[j], acc[i][j]);
            __syncthreads();
        }
        float* dst = Ppart + (size_t)ks * 589824;
#pragma unroll
        for (int i = 0; i < 4; i++)
#pragma unroll
            for (int j = 0; j < 4; j++) {
                int col = nt * 128 + wn * 64 + j * 16 + l16;
#pragma unroll
                for (int q = 0; q < 4; q++) {
                    int row = mt * 128 + wm * 64 + i * 16 + lk * 4 + q;
                    dst[(size_t)row * HH + col] = acc[i][j][q];
                }
            }
    } else {
        int idx = bid - 288;
        int nt = idx >> 3, ks = idx & 7;
        int kb = ks * 12;
        const uint4* Ag0 = Wcomb + (size_t)(wave * 32 + srow) * 192 + kb + schk;
        const uint4* Ag1 = Ag0 + (size_t)16 * 192;
        const uint4* Bg0 = WvT + (size_t)(nt * 128 + wave * 32 + srow) * 96 + kb + schk;
        const uint4* Bg1 = Bg0 + (size_t)16 * 96;
        uint4* sA0 = &sAh[wave * 128];
        uint4* sA1 = sA0 + 64;
        uint4* sB0 = &sBh[wave * 128];
        uint4* sB1 = sB0 + 64;
        for (int k0 = 0; k0 < 12; k0 += 4) {
            gload16(Ag0 + k0, sA0); gload16(Ag1 + k0, sA1);
            gload16(Bg0 + k0, sB0); gload16(Bg1 + k0, sB1);
            __syncthreads();
            bf16x8 af[4], bfr[4];
#pragma unroll
            for (int i = 0; i < 4; i++)
                af[i] = *reinterpret_cast<const bf16x8*>(&sAh[(wm * 64 + i * 16 + l16) * 4 + lk]);
#pragma unroll
            for (int j = 0; j < 4; j++)
                bfr[j] = *reinterpret_cast<const bf16x8*>(&sBh[(wn * 64 + j * 16 + l16) * 4 + lk]);
#pragma unroll
            for (int i = 0; i < 4; i++)
#pragma unroll
                for (int j = 0; j < 4; j++)
                    acc[i][j] = MF(af[i], bfr[j], acc[i][j]);
            __syncthreads();
        }
        float* dst = WRpart + (size_t)ks * 98304;
#pragma unroll
        for (int i = 0; i < 4; i++)
#pragma unroll
            for (int j = 0; j < 4; j++) {
                int col = nt * 128 + wn * 64 + j * 16 + l16;
#pragma unroll
                for (int q = 0; q < 4; q++) {
                    int row = wm * 64 + i * 16 + lk * 4 + q;
                    dst[(size_t)row * HH + col] = acc[i][j][q];
                }
            }
    }
}

// ================= K3: reductions =================
__global__ __launch_bounds__(256) void psum_kernel(
    const float4* __restrict__ Ppart, ushort4* __restrict__ Pb,
    const float4* __restrict__ WRpart, unsigned short* __restrict__ Wcomb,
    const float* __restrict__ u_part, float* __restrict__ u,
    const float* __restrict__ wsbv_part, float* __restrict__ wsbv)
{
    int bid = blockIdx.x, t = threadIdx.x;
    if (bid < 576) {
        int i = bid * 256 + t;   // float4 idx, 147456 total
        float4 s = Ppart[i];
#pragma unroll
        for (int k = 1; k < 8; k++) {
            float4 v = Ppart[(size_t)k * 147456 + i];
            s.x += v.x; s.y += v.y; s.z += v.z; s.w += v.w;
        }
        ushort4 o;
        o.x = f2bf(s.x); o.y = f2bf(s.y); o.z = f2bf(s.z); o.w = f2bf(s.w);
        Pb[i] = o;
    } else if (bid < 672) {
        int q = (bid - 576) * 256 + t;   // 0..24575 over 128x768 (float4)
        float4 s = WRpart[q];
#pragma unroll
        for (int k = 1; k < 8; k++) {
            float4 v = WRpart[(size_t)k * 24576 + q];
            s.x += v.x; s.y += v.y; s.z += v.z; s.w += v.w;
        }
        int row = q / 192, colq = q % 192;
        ushort4 o;
        o.x = f2bf(s.x); o.y = f2bf(s.y); o.z = f2bf(s.z); o.w = f2bf(s.w);
        *reinterpret_cast<ushort4*>(&Wcomb[row * 1536 + 768 + colq * 4]) = o;
    } else if (bid < 675) {
        int c = (bid - 672) * 256 + t;
        float s = 0.f;
#pragma unroll
        for (int ty = 0; ty < 12; ty++) s += u_part[ty * HH + c];
        u[c] = s;
    } else if (t < 128) {
        wsbv[t] = wsbv_part[t] + wsbv_part[128 + t] + wsbv_part[256 + t];
    }
}

// ================= K4': qp GEMM (768 blocks, bf16 out) + slot-left (256) =====
__global__ __launch_bounds__(256) void gemm_qp_sl(
    const uint4* __restrict__ A,   // slotA [8192][192]
    const uint4* __restrict__ Bm,  // Pb [768][96]
    const uint4* __restrict__ Wc,  // Wcomb [128][192]
    const float* __restrict__ u,
    unsigned short* __restrict__ qp,  // [8192][768] bf16
    float* __restrict__ Cpart0)       // [8192][128]
{
    __shared__ uint4 sA[256];
    __shared__ uint4 sB[512];

    int bid = blockIdx.x;
    int t = threadIdx.x;
    int lane = t & 63, wave = t >> 6;
    int wm = wave >> 1, wn = wave & 1;
    int l16 = lane & 15, lk = lane >> 4;
    int srow = lane >> 2, schk = lane & 3;

    if (bid >= 768) {            // ---- slot-left: 32x128 tile ----
        int mt = bid - 768;      // 0..255
        const uint4* Ag  = A + (size_t)(mt * 32 + wave * 16 + srow) * 192 + schk; // waves 0,1 only
        const uint4* Bg0 = Wc + (size_t)(wave * 32 + srow) * 192 + schk;
        const uint4* Bg1 = Bg0 + (size_t)16 * 192;
        uint4* sB0 = &sB[wave * 128];
        uint4* sB1 = &sB[wave * 128 + 64];

        f32x4 acc[4] = {};
        for (int k0 = 0; k0 < 96; k0 += 4) {
            if (wave < 2) gload16(Ag + k0, &sA[wave * 64]);
            gload16(Bg0 + k0, sB0);
            gload16(Bg1 + k0, sB1);
            __syncthreads();
            bf16x8 af = *reinterpret_cast<const bf16x8*>(&sA[(wm * 16 + l16) * 4 + lk]);
            bf16x8 bfr[4];
#pragma unroll
            for (int j = 0; j < 4; j++)
                bfr[j] = *reinterpret_cast<const bf16x8*>(&sB[(wn * 64 + j * 16 + l16) * 4 + lk]);
#pragma unroll
            for (int j = 0; j < 4; j++)
                acc[j] = MF(af, bfr[j], acc[j]);
            __syncthreads();
        }
#pragma unroll
        for (int j = 0; j < 4; j++) {
            int col = wn * 64 + j * 16 + l16;
#pragma unroll
            for (int q = 0; q < 4; q++) {
                int row = mt * 32 + wm * 16 + lk * 4 + q;
                Cpart0[(size_t)row * 128 + col] = acc[j][q];
            }
        }
        return;
    }

    // ---- qp: 64x128 tile, XCD swizzle over 768 ----
    bid = (bid & 7) * 96 + (bid >> 3);
    int mt = bid / 6, nt = bid % 6;

    const uint4* Ag  = A + (size_t)(mt * 64 + wave * 16 + srow) * 192 + schk;
    const uint4* Bg0 = Bm + (size_t)(nt * 128 + wave * 32 + srow) * 96 + schk;
    const uint4* Bg1 = Bg0 + (size_t)16 * 96;
    uint4* sAp = &sA[wave * 64];
    uint4* sB0 = &sB[wave * 128];
    uint4* sB1 = &sB[wave * 128 + 64];

    f32x4 acc[2][4] = {};

    for (int k0 = 0; k0 < 96; k0 += 4) {
        gload16(Ag + k0, sAp);
        gload16(Bg0 + k0, sB0);
        gload16(Bg1 + k0, sB1);
        __syncthreads();
        bf16x8 af[2], bfr[4];
#pragma unroll
        for (int i = 0; i < 2; i++)
            af[i] = *reinterpret_cast<const bf16x8*>(&sA[(wm * 32 + i * 16 + l16) * 4 + lk]);
#pragma unroll
        for (int j = 0; j < 4; j++)
            bfr[j] = *reinterpret_cast<const bf16x8*>(&sB[(wn * 64 + j * 16 + l16) * 4 + lk]);
#pragma unroll
        for (int i = 0; i < 2; i++)
#pragma unroll
            for (int j = 0; j < 4; j++)
                acc[i][j] = MF(af[i], bfr[j], acc[i][j]);
        __syncthreads();
    }

#pragma unroll
    for (int i = 0; i < 2; i++)
#pragma unroll
        for (int j = 0; j < 4; j++) {
            int col = nt * 128 + wn * 64 + j * 16 + l16;
            float add = u[col];
#pragma unroll
            for (int q = 0; q < 4; q++) {
                int row = mt * 64 + wm * 32 + i * 16 + lk * 4 + q;
                qp[(size_t)row * HH + col] = f2bf(acc[i][j][q] + add);
            }
        }
}

// ================= K5: flash attention (bf16 qp, online softmax) ============
__global__ __launch_bounds__(256) void attn2_kernel(
    const unsigned short* __restrict__ qp,  // [8192][768] bf16
    const float* __restrict__ res_all,      // [B*S][768] f32
    const int* __restrict__ starts,
    const int* __restrict__ lens,
    unsigned short* __restrict__ slotA)     // [8192][1536], writes cols 768..1535
{
    int bid = blockIdx.x;
    bid = (bid & 7) * 256 + (bid >> 3);              // 2048 = 8 x 256
    int gw = bid * 4 + (threadIdx.x >> 6);
    int lane = threadIdx.x & 63;
    int b = gw >> 8;
    int s0 = starts[gw];
    int sl = lens[gw];                               // 1..7, wave-uniform

    unsigned short* dst = slotA + (size_t)gw * 1536 + 768 + lane * 12;

    if (sl == 1) {                                   // word = first; xbar half = 0
        ushort4 z = {0, 0, 0, 0};
#pragma unroll
        for (int c = 0; c < 3; c++) *reinterpret_cast<ushort4*>(&dst[c * 4]) = z;
        return;
    }

    const unsigned short* qrow = qp + (size_t)gw * HH + lane * 12;
    float q[12];
#pragma unroll
    for (int c = 0; c < 3; c++) {
        ushort4 v = *reinterpret_cast<const ushort4*>(&qrow[c * 4]);
        q[c * 4 + 0] = bf2f(v.x); q[c * 4 + 1] = bf2f(v.y);
        q[c * 4 + 2] = bf2f(v.z); q[c * 4 + 3] = bf2f(v.w);
    }

    float m = -1e30f, ssum = 0.f;
    float acc[12];
#pragma unroll
    for (int i = 0; i < 12; i++) acc[i] = 0.f;

    for (int k = 0; k < LL; k++) {
        if (k > sl) break;                           // uniform branch
        int s = s0 + k; if (s > SS - 1) s = SS - 1;
        const float* xr = res_all + (size_t)(b * SS + s) * HH + lane * 12;
        float x[12];
        float partial = 0.f;
#pragma unroll
        for (int c = 0; c < 3; c++) {
            float4 v = *reinterpret_cast<const float4*>(&xr[c * 4]);
            x[c * 4 + 0] = v.x; x[c * 4 + 1] = v.y;
            x[c * 4 + 2] = v.z; x[c * 4 + 3] = v.w;
            partial += q[c * 4 + 0] * v.x + q[c * 4 + 1] * v.y
                     + q[c * 4 + 2] * v.z + q[c * 4 + 3] * v.w;
        }
#pragma unroll
        for (int off = 32; off > 0; off >>= 1) partial += __shfl_xor(partial, off);

        float mnew = (partial > m) ? partial : m;
        float scale = __expf(m - mnew);
        float e = __expf(partial - mnew);
        ssum = ssum * scale + e;
#pragma unroll
        for (int i = 0; i < 12; i++) acc[i] = acc[i] * scale + e * x[i];
        m = mnew;
    }

    float inv = 1.f / ssum;
#pragma unroll
    for (int c = 0; c < 3; c++) {
        ushort4 o;
        o.x = f2bf(acc[c * 4 + 0] * inv); o.y = f2bf(acc[c * 4 + 1] * inv);
        o.z = f2bf(acc[c * 4 + 2] * inv); o.w = f2bf(acc[c * 4 + 3] * inv);
        *reinterpret_cast<ushort4*>(&dst[c * 4]) = o;
    }
}

// ================= K6: slot-right GEMM + merge (32x128 tiles, 256 blocks) ===
__global__ __launch_bounds__(256) void gemm_slot_r(
    const uint4* __restrict__ A,    // slotA [8192][192]
    const uint4* __restrict__ Bm,   // Wcomb [128][192]
    const float* __restrict__ Cpart0,
    const float* __restrict__ bias, const float* __restrict__ wsbv,
    const int* __restrict__ lens,
    float* __restrict__ outsf)      // [8192][121]
{
    __shared__ uint4 sA[128];   // 32 rows
    __shared__ uint4 sB[512];   // 128 rows

    int mt = blockIdx.x;
    int t = threadIdx.x;
    int lane = t & 63, wave = t >> 6;
    int wm = wave >> 1, wn = wave & 1;
    int l16 = lane & 15, lk = lane >> 4;
    int srow = lane >> 2, schk = lane & 3;

    const uint4* Ag  = A + (size_t)(mt * 32 + wave * 16 + srow) * 192 + 96 + schk;
    const uint4* Bg0 = Bm + (size_t)(wave * 32 + srow) * 192 + 96 + schk;
    const uint4* Bg1 = Bg0 + (size_t)16 * 192;
    uint4* sB0 = &sB[wave * 128];
    uint4* sB1 = &sB[wave * 128 + 64];

    f32x4 acc[4] = {};

    for (int k0 = 0; k0 < 96; k0 += 4) {
        if (wave < 2) gload16(Ag + k0, &sA[wave * 64]);
        gload16(Bg0 + k0, sB0);
        gload16(Bg1 + k0, sB1);
        __syncthreads();
        bf16x8 af = *reinterpret_cast<const bf16x8*>(&sA[(wm * 16 + l16) * 4 + lk]);
        bf16x8 bfr[4];
#pragma unroll
        for (int j = 0; j < 4; j++)
            bfr[j] = *reinterpret_cast<const bf16x8*>(&sB[(wn * 64 + j * 16 + l16) * 4 + lk]);
#pragma unroll
        for (int j = 0; j < 4; j++)
            acc[j] = MF(af, bfr[j], acc[j]);
        __syncthreads();
    }

#pragma unroll
    for (int j = 0; j < 4; j++) {
        int col = wn * 64 + j * 16 + l16;
        if (col < NSLOT) {
            float bc = bias[col], wv = wsbv[col];
#pragma unroll
            for (int q = 0; q < 4; q++) {
                int row = mt * 32 + wm * 16 + lk * 4 + q;
                float v = acc[j][q] + Cpart0[(size_t)row * 128 + col]
                        + bc + ((lens[row] > 1) ? wv : 0.f);
                outsf[(size_t)row * NSLOT + col] = v;
            }
        }
    }
}

// ---------------- launch ----------------
extern "C" void kernel_launch(void* const* d_in, const int* in_sizes, int n_in,
                              void* d_out, int out_size, void* d_ws, size_t ws_size,
                              hipStream_t stream) {
    const float* res_all    = (const float*)d_in[0];
    const float* res        = (const float*)d_in[1];
    const int*   starts     = (const int*)d_in[2];
    const int*   lens       = (const int*)d_in[3];
    const float* Wsq_w      = (const float*)d_in[4];
    const float* Wsq_b      = (const float*)d_in[5];
    const float* Wsk_w      = (const float*)d_in[6];
    const float* Wsk_b      = (const float*)d_in[7];
    const float* Wsv_w      = (const float*)d_in[8];
    const float* Wsv_b      = (const float*)d_in[9];
    const float* lin_id_w   = (const float*)d_in[10];
    const float* lin_id_b   = (const float*)d_in[11];
    const float* lin_slot_w = (const float*)d_in[12];
    const float* lin_slot_b = (const float*)d_in[13];
    float* out = (float*)d_out;
    (void)Wsk_b;  // softmax-invariant (constant over k)

    char* ws = (char*)d_ws;
    unsigned short* slotA     = (unsigned short*)(ws + 0);          // 8192x1536 bf16
    unsigned short* qp        = (unsigned short*)(ws + 25165824);   // 8192x768 bf16
    unsigned short* WkT_hi    = (unsigned short*)(ws + 50331648);
    unsigned short* WkT_lo    = (unsigned short*)(ws + 51511296);
    unsigned short* WqT_hi    = (unsigned short*)(ws + 52690944);
    unsigned short* WqT_lo    = (unsigned short*)(ws + 53870592);
    unsigned short* WvT       = (unsigned short*)(ws + 55050240);
    unsigned short* Pb        = (unsigned short*)(ws + 56229888);   // 768^2 bf16
    unsigned short* Wcomb     = (unsigned short*)(ws + 57409536);   // 128x1536 bf16
    float*          u         = (float*)(ws + 57802752);            // 768
    float*          wsbv      = (float*)(ws + 57805824);            // 128
    float*          u_part    = (float*)(ws + 57806336);            // 12x768
    float*          wsbv_part = (float*)(ws + 57843200);            // 3x128
    float*          Ppart     = (float*)(ws + 57845760);            // 8x768x768 f32
    float*          WRpart    = (float*)(ws + 76720128);            // 8x128x768 f32
    float*          Cpart0    = (float*)(ws + 79865856);            // 8192x128 f32

    // K1: weight prep
    prep_w<<<816, 256, 0, stream>>>(
        Wsk_w, Wsq_w, Wsv_w, lin_slot_w, Wsq_b, Wsv_b,
        WkT_hi, WkT_lo, WqT_hi, WqT_lo, WvT, Wcomb,
        u_part, wsbv_part);

    // K2: weight GEMMs + gather + res_id
    gemm_weights<<<2592, 256, 0, stream>>>(
        (const uint4*)WkT_hi, (const uint4*)WkT_lo,
        (const uint4*)WqT_hi, (const uint4*)WqT_lo,
        (const uint4*)WvT, (const uint4*)Wcomb,
        res_all, starts, res, lin_id_w, lin_id_b,
        Ppart, WRpart, slotA, out);

    // K3: reductions
    psum_kernel<<<676, 256, 0, stream>>>(
        (const float4*)Ppart, (ushort4*)Pb, (const float4*)WRpart, Wcomb,
        u_part, u, wsbv_part, wsbv);

    // K4': qp GEMM (bf16 out) + slot-left GEMM (overlapped in one launch)
    gemm_qp_sl<<<1024, 256, 0, stream>>>((const uint4*)slotA, (const uint4*)Pb,
                                         (const uint4*)Wcomb, u, qp, Cpart0);

    // K5: flash attention -> slotA right half
    attn2_kernel<<<2048, 256, 0, stream>>>(qp, res_all, starts, lens, slotA);

    // K6: slot-right GEMM + merge -> out
    gemm_slot_r<<<256, 256, 0, stream>>>((const uint4*)slotA, (const uint4*)Wcomb,
                                         Cpart0, lin_slot_b, wsbv, lens, out + 832);
}

// Round 15
// 83.989 us; speedup vs baseline: 1.2043x; 1.0049x over previous
//
#include <hip/hip_runtime.h>
#include <cstdint>
#include <cstddef>

// Problem constants
#define BB 32
#define SS 512
#define HH 768
#define WW 256
#define LL 8
#define NINTENT 26
#define NSLOT 121

typedef float f32x4 __attribute__((ext_vector_type(4)));
typedef __bf16 bf16x8 __attribute__((ext_vector_type(8)));

static __device__ __forceinline__ float bf2f(unsigned short u) {
    union { unsigned int i; float f; } x; x.i = ((unsigned int)u) << 16; return x.f;
}
static __device__ __forceinline__ unsigned short f2bf(float f) {
    union { float f; unsigned int i; } x; x.f = f;
    unsigned int r = (x.i + 0x7fffu + ((x.i >> 16) & 1u)) >> 16;
    return (unsigned short)r;
}

// async global->LDS, 16B per lane, wave-uniform LDS base + lane*16
static __device__ __forceinline__ void gload16(const void* g, void* l) {
    __builtin_amdgcn_global_load_lds(
        (const __attribute__((address_space(1))) void*)g,
        (__attribute__((address_space(3))) void*)l, 16, 0, 0);
}

#define MF(a, b, c) __builtin_amdgcn_mfma_f32_16x16x32_bf16((a), (b), (c), 0, 0, 0)

// ================= K1: weight prep =================
// [0,432):   64x64 transpose + hi/lo split (Wk,Wq) / hi (Wv); Wk also u-partials
// [432,816): Wcomb left copy (bf16 Ws, zero pad) + wsbv partials
__global__ __launch_bounds__(256) void prep_w(
    const float* __restrict__ Wk, const float* __restrict__ Wq,
    const float* __restrict__ Wv, const float* __restrict__ Ws,
    const float* __restrict__ bq, const float* __restrict__ bv,
    unsigned short* __restrict__ WkT_hi, unsigned short* __restrict__ WkT_lo,
    unsigned short* __restrict__ WqT_hi, unsigned short* __restrict__ WqT_lo,
    unsigned short* __restrict__ WvT, unsigned short* __restrict__ Wcomb,
    float* __restrict__ u_part,     // [12][768]
    float* __restrict__ wsbv_part)  // [3][128]
{
    int bid = blockIdx.x;
    int t = threadIdx.x;

    if (bid < 432) {
        __shared__ float tl[64][65];
        int mb = bid / 144, tb = bid % 144;
        int tx = tb % 12, ty = tb / 12;
        const float* src = (mb == 0) ? Wk : (mb == 1) ? Wq : Wv;
        int rr = t >> 4, c4 = (t & 15) * 4;
#pragma unroll
        for (int j = 0; j < 4; j++) {
            float4 v = *reinterpret_cast<const float4*>(
                &src[(size_t)(ty * 64 + rr + 16 * j) * HH + tx * 64 + c4]);
            tl[rr + 16 * j][c4 + 0] = v.x; tl[rr + 16 * j][c4 + 1] = v.y;
            tl[rr + 16 * j][c4 + 2] = v.z; tl[rr + 16 * j][c4 + 3] = v.w;
        }
        __syncthreads();
        int il = t >> 4, o4 = (t & 15) * 4;
        unsigned short* dhi = (mb == 0) ? WkT_hi : (mb == 1) ? WqT_hi : WvT;
        unsigned short* dlo = (mb == 0) ? WkT_lo : WqT_lo;  // unused when mb==2
#pragma unroll
        for (int j = 0; j < 4; j++) {
            int i = il + 16 * j;
            float v0 = tl[o4 + 0][i], v1 = tl[o4 + 1][i];
            float v2 = tl[o4 + 2][i], v3 = tl[o4 + 3][i];
            size_t off = (size_t)(tx * 64 + i) * HH + ty * 64 + o4;
            ushort4 h;
            h.x = f2bf(v0); h.y = f2bf(v1); h.z = f2bf(v2); h.w = f2bf(v3);
            *reinterpret_cast<ushort4*>(&dhi[off]) = h;
            if (mb < 2) {
                ushort4 l;
                l.x = f2bf(v0 - bf2f(h.x)); l.y = f2bf(v1 - bf2f(h.y));
                l.z = f2bf(v2 - bf2f(h.z)); l.w = f2bf(v3 - bf2f(h.w));
                *reinterpret_cast<ushort4*>(&dlo[off]) = l;
            }
        }
        if (mb == 0) {
            int c = t >> 2, q = t & 3;
            float s = 0.f;
#pragma unroll
            for (int r = 0; r < 16; r++)
                s += bq[ty * 64 + q * 16 + r] * tl[q * 16 + r][c];
            s += __shfl_xor(s, 1);
            s += __shfl_xor(s, 2);
            if (q == 0) u_part[ty * HH + tx * 64 + c] = s;
        }
    } else {
        __shared__ float wred[4];
        int bid2 = bid - 432;
        int idx = bid2 * 256 + t;         // 0..98303 over 128x768
        int row = idx / HH, col = idx % HH;
        float v = (row < NSLOT) ? Ws[row * HH + col] : 0.f;
        Wcomb[row * 1536 + col] = f2bf(v);
        float pv = v * bv[col];
        int lane = t & 63, wave = t >> 6;
#pragma unroll
        for (int off = 32; off > 0; off >>= 1) pv += __shfl_xor(pv, off);
        if (lane == 0) wred[wave] = pv;
        __syncthreads();
        if (t == 0)
            wsbv_part[(bid2 % 3) * 128 + row] = wred[0] + wred[1] + wred[2] + wred[3];
    }
}

// ================= K2: weight GEMMs (128x128, K-split x4) + gather + res_id =
// [0,144):    G1: Ppart[ks] = hi.hi + lo.hi + hi.lo (4-buffer staging, 24 chunks)
// [144,168):  G2: WRpart[ks] = Ws . WvT^T over k-slice (24 chunks)
// [168,2216): gather first rows -> slotA left half
// [2216,2424): res_id, one wave per (bb, o)
__global__ __launch_bounds__(256) void gemm_weights(
    const uint4* __restrict__ WkT_hi, const uint4* __restrict__ WkT_lo,
    const uint4* __restrict__ WqT_hi, const uint4* __restrict__ WqT_lo,
    const uint4* __restrict__ WvT, const uint4* __restrict__ Wcomb,
    const float* __restrict__ res_all, const int* __restrict__ starts,
    const float* __restrict__ res, const float* __restrict__ id_w,
    const float* __restrict__ id_b,
    float* __restrict__ Ppart,   // [4][768][768]
    float* __restrict__ WRpart,  // [4][128][768]
    unsigned short* __restrict__ slotA,  // [8192][1536]
    float* __restrict__ out)
{
    __shared__ uint4 sAh[512];
    __shared__ uint4 sAl[512];
    __shared__ uint4 sBh[512];
    __shared__ uint4 sBl[512];
    int bid = blockIdx.x;
    int t = threadIdx.x;
    int lane = t & 63, wave = t >> 6;

    if (bid >= 2216) {           // ---- res_id: wave per (bb, o) ----
        int w = (bid - 2216) * 4 + wave;   // 0..831
        int bb = w / 26, o = w - bb * 26;
        const float* rrow = res + bb * HH + lane * 12;
        const float* wrow = id_w + o * HH + lane * 12;
        float s = 0.f;
#pragma unroll
        for (int c = 0; c < 3; c++) {
            float4 a = *reinterpret_cast<const float4*>(&rrow[c * 4]);
            float4 b = *reinterpret_cast<const float4*>(&wrow[c * 4]);
            s += a.x * b.x + a.y * b.y + a.z * b.z + a.w * b.w;
        }
#pragma unroll
        for (int off = 32; off > 0; off >>= 1) s += __shfl_xor(s, off);
        if (lane == 0) out[bb * NINTENT + o] = s + id_b[o];
        return;
    }
    if (bid >= 168) {            // ---- gather first rows ----
        int gw = (bid - 168) * 4 + wave;
        int b = gw >> 8;
        int s0 = starts[gw];
        const float* src = res_all + (size_t)(b * SS + s0) * HH + lane * 12;
        unsigned short* dst = slotA + (size_t)gw * 1536 + lane * 12;
#pragma unroll
        for (int c2 = 0; c2 < 3; c2++) {
            float4 v = *reinterpret_cast<const float4*>(&src[c2 * 4]);
            ushort4 o;
            o.x = f2bf(v.x); o.y = f2bf(v.y); o.z = f2bf(v.z); o.w = f2bf(v.w);
            *reinterpret_cast<ushort4*>(&dst[c2 * 4]) = o;
        }
        return;
    }

    int wm = wave >> 1, wn = wave & 1;
    int l16 = lane & 15, lk = lane >> 4;
    int srow = lane >> 2, schk = lane & 3;

    f32x4 acc[4][4] = {};

    if (bid < 144) {             // ---- G1: 4-buffer staging, ks in [0,4) ----
        int tile = bid >> 2, ks = bid & 3;
        int mt = tile / 6, nt = tile % 6;
        int kb = ks * 24;
        size_t aoff = (size_t)(mt * 128 + wave * 32 + srow) * 96 + kb + schk;
        size_t boff = (size_t)(nt * 128 + wave * 32 + srow) * 96 + kb + schk;
        const uint4* Ah0 = WkT_hi + aoff; const uint4* Ah1 = Ah0 + (size_t)16 * 96;
        const uint4* Al0 = WkT_lo + aoff; const uint4* Al1 = Al0 + (size_t)16 * 96;
        const uint4* Bh0 = WqT_hi + boff; const uint4* Bh1 = Bh0 + (size_t)16 * 96;
        const uint4* Bl0 = WqT_lo + boff; const uint4* Bl1 = Bl0 + (size_t)16 * 96;
        uint4* dAh0 = &sAh[wave * 128]; uint4* dAh1 = dAh0 + 64;
        uint4* dAl0 = &sAl[wave * 128]; uint4* dAl1 = dAl0 + 64;
        uint4* dBh0 = &sBh[wave * 128]; uint4* dBh1 = dBh0 + 64;
        uint4* dBl0 = &sBl[wave * 128]; uint4* dBl1 = dBl0 + 64;

        for (int k0 = 0; k0 < 24; k0 += 4) {
            gload16(Ah0 + k0, dAh0); gload16(Ah1 + k0, dAh1);
            gload16(Al0 + k0, dAl0); gload16(Al1 + k0, dAl1);
            gload16(Bh0 + k0, dBh0); gload16(Bh1 + k0, dBh1);
            gload16(Bl0 + k0, dBl0); gload16(Bl1 + k0, dBl1);
            __syncthreads();
            bf16x8 afh[4], afl[4], bfh[4], bfl[4];
#pragma unroll
            for (int i = 0; i < 4; i++) {
                int ro = (wm * 64 + i * 16 + l16) * 4 + lk;
                afh[i] = *reinterpret_cast<const bf16x8*>(&sAh[ro]);
                afl[i] = *reinterpret_cast<const bf16x8*>(&sAl[ro]);
            }
#pragma unroll
            for (int j = 0; j < 4; j++) {
                int ro = (wn * 64 + j * 16 + l16) * 4 + lk;
                bfh[j] = *reinterpret_cast<const bf16x8*>(&sBh[ro]);
                bfl[j] = *reinterpret_cast<const bf16x8*>(&sBl[ro]);
            }
#pragma unroll
            for (int i = 0; i < 4; i++)
#pragma unroll
                for (int j = 0; j < 4; j++)
                    acc[i][j] = MF(afh[i], bfh[j], acc[i][j]);
#pragma unroll
            for (int i = 0; i < 4; i++)
#pragma unroll
                for (int j = 0; j < 4; j++)
                    acc[i][j] = MF(afl[i], bfh[j], acc[i][j]);
#pragma unroll
            for (int i = 0; i < 4; i++)
#pragma unroll
                for (int j = 0; j < 4; j++)
                    acc[i][j] = MF(afh[i], bfl[j], acc[i][j]);
            __syncthreads();
        }
        float* dst = Ppart + (size_t)ks * 589824;
#pragma unroll
        for (int i = 0; i < 4; i++)
#pragma unroll
            for (int j = 0; j < 4; j++) {
                int col = nt * 128 + wn * 64 + j * 16 + l16;
#pragma unroll
                for (int q = 0; q < 4; q++) {
                    int row = mt * 128 + wm * 64 + i * 16 + lk * 4 + q;
                    dst[(size_t)row * HH + col] = acc[i][j][q];
                }
            }
    } else {                     // ---- G2: ks in [0,4) ----
        int idx = bid - 144;
        int nt = idx >> 2, ks = idx & 3;
        int kb = ks * 24;
        const uint4* Ag0 = Wcomb + (size_t)(wave * 32 + srow) * 192 + kb + schk;
        const uint4* Ag1 = Ag0 + (size_t)16 * 192;
        const uint4* Bg0 = WvT + (size_t)(nt * 128 + wave * 32 + srow) * 96 + kb + schk;
        const uint4* Bg1 = Bg0 + (size_t)16 * 96;
        uint4* sA0 = &sAh[wave * 128];
        uint4* sA1 = sA0 + 64;
        uint4* sB0 = &sBh[wave * 128];
        uint4* sB1 = sB0 + 64;
        for (int k0 = 0; k0 < 24; k0 += 4) {
            gload16(Ag0 + k0, sA0); gload16(Ag1 + k0, sA1);
            gload16(Bg0 + k0, sB0); gload16(Bg1 + k0, sB1);
            __syncthreads();
            bf16x8 af[4], bfr[4];
#pragma unroll
            for (int i = 0; i < 4; i++)
                af[i] = *reinterpret_cast<const bf16x8*>(&sAh[(wm * 64 + i * 16 + l16) * 4 + lk]);
#pragma unroll
            for (int j = 0; j < 4; j++)
                bfr[j] = *reinterpret_cast<const bf16x8*>(&sBh[(wn * 64 + j * 16 + l16) * 4 + lk]);
#pragma unroll
            for (int i = 0; i < 4; i++)
#pragma unroll
                for (int j = 0; j < 4; j++)
                    acc[i][j] = MF(af[i], bfr[j], acc[i][j]);
            __syncthreads();
        }
        float* dst = WRpart + (size_t)ks * 98304;
#pragma unroll
        for (int i = 0; i < 4; i++)
#pragma unroll
            for (int j = 0; j < 4; j++) {
                int col = nt * 128 + wn * 64 + j * 16 + l16;
#pragma unroll
                for (int q = 0; q < 4; q++) {
                    int row = wm * 64 + i * 16 + lk * 4 + q;
                    dst[(size_t)row * HH + col] = acc[i][j][q];
                }
            }
    }
}

// ================= K3: reductions (4 partials) =================
__global__ __launch_bounds__(256) void psum_kernel(
    const float4* __restrict__ Ppart, ushort4* __restrict__ Pb,
    const float4* __restrict__ WRpart, unsigned short* __restrict__ Wcomb,
    const float* __restrict__ u_part, float* __restrict__ u,
    const float* __restrict__ wsbv_part, float* __restrict__ wsbv)
{
    int bid = blockIdx.x, t = threadIdx.x;
    if (bid < 576) {
        int i = bid * 256 + t;   // float4 idx, 147456 total
        float4 s = Ppart[i];
#pragma unroll
        for (int k = 1; k < 4; k++) {
            float4 v = Ppart[(size_t)k * 147456 + i];
            s.x += v.x; s.y += v.y; s.z += v.z; s.w += v.w;
        }
        ushort4 o;
        o.x = f2bf(s.x); o.y = f2bf(s.y); o.z = f2bf(s.z); o.w = f2bf(s.w);
        Pb[i] = o;
    } else if (bid < 672) {
        int q = (bid - 576) * 256 + t;   // 0..24575 over 128x768 (float4)
        float4 s = WRpart[q];
#pragma unroll
        for (int k = 1; k < 4; k++) {
            float4 v = WRpart[(size_t)k * 24576 + q];
            s.x += v.x; s.y += v.y; s.z += v.z; s.w += v.w;
        }
        int row = q / 192, colq = q % 192;
        ushort4 o;
        o.x = f2bf(s.x); o.y = f2bf(s.y); o.z = f2bf(s.z); o.w = f2bf(s.w);
        *reinterpret_cast<ushort4*>(&Wcomb[row * 1536 + 768 + colq * 4]) = o;
    } else if (bid < 675) {
        int c = (bid - 672) * 256 + t;
        float s = 0.f;
#pragma unroll
        for (int ty = 0; ty < 12; ty++) s += u_part[ty * HH + c];
        u[c] = s;
    } else if (t < 128) {
        wsbv[t] = wsbv_part[t] + wsbv_part[128 + t] + wsbv_part[256 + t];
    }
}

// ================= K4': qp GEMM (768 blocks, bf16 out) + slot-left (256) =====
__global__ __launch_bounds__(256) void gemm_qp_sl(
    const uint4* __restrict__ A,   // slotA [8192][192]
    const uint4* __restrict__ Bm,  // Pb [768][96]
    const uint4* __restrict__ Wc,  // Wcomb [128][192]
    const float* __restrict__ u,
    unsigned short* __restrict__ qp,  // [8192][768] bf16
    float* __restrict__ Cpart0)       // [8192][128]
{
    __shared__ uint4 sA[256];
    __shared__ uint4 sB[512];

    int bid = blockIdx.x;
    int t = threadIdx.x;
    int lane = t & 63, wave = t >> 6;
    int wm = wave >> 1, wn = wave & 1;
    int l16 = lane & 15, lk = lane >> 4;
    int srow = lane >> 2, schk = lane & 3;

    if (bid >= 768) {            // ---- slot-left: 32x128 tile ----
        int mt = bid - 768;      // 0..255
        const uint4* Ag  = A + (size_t)(mt * 32 + wave * 16 + srow) * 192 + schk; // waves 0,1 only
        const uint4* Bg0 = Wc + (size_t)(wave * 32 + srow) * 192 + schk;
        const uint4* Bg1 = Bg0 + (size_t)16 * 192;
        uint4* sB0 = &sB[wave * 128];
        uint4* sB1 = &sB[wave * 128 + 64];

        f32x4 acc[4] = {};
        for (int k0 = 0; k0 < 96; k0 += 4) {
            if (wave < 2) gload16(Ag + k0, &sA[wave * 64]);
            gload16(Bg0 + k0, sB0);
            gload16(Bg1 + k0, sB1);
            __syncthreads();
            bf16x8 af = *reinterpret_cast<const bf16x8*>(&sA[(wm * 16 + l16) * 4 + lk]);
            bf16x8 bfr[4];
#pragma unroll
            for (int j = 0; j < 4; j++)
                bfr[j] = *reinterpret_cast<const bf16x8*>(&sB[(wn * 64 + j * 16 + l16) * 4 + lk]);
#pragma unroll
            for (int j = 0; j < 4; j++)
                acc[j] = MF(af, bfr[j], acc[j]);
            __syncthreads();
        }
#pragma unroll
        for (int j = 0; j < 4; j++) {
            int col = wn * 64 + j * 16 + l16;
#pragma unroll
            for (int q = 0; q < 4; q++) {
                int row = mt * 32 + wm * 16 + lk * 4 + q;
                Cpart0[(size_t)row * 128 + col] = acc[j][q];
            }
        }
        return;
    }

    // ---- qp: 64x128 tile, XCD swizzle over 768 ----
    bid = (bid & 7) * 96 + (bid >> 3);
    int mt = bid / 6, nt = bid % 6;

    const uint4* Ag  = A + (size_t)(mt * 64 + wave * 16 + srow) * 192 + schk;
    const uint4* Bg0 = Bm + (size_t)(nt * 128 + wave * 32 + srow) * 96 + schk;
    const uint4* Bg1 = Bg0 + (size_t)16 * 96;
    uint4* sAp = &sA[wave * 64];
    uint4* sB0 = &sB[wave * 128];
    uint4* sB1 = &sB[wave * 128 + 64];

    f32x4 acc[2][4] = {};

    for (int k0 = 0; k0 < 96; k0 += 4) {
        gload16(Ag + k0, sAp);
        gload16(Bg0 + k0, sB0);
        gload16(Bg1 + k0, sB1);
        __syncthreads();
        bf16x8 af[2], bfr[4];
#pragma unroll
        for (int i = 0; i < 2; i++)
            af[i] = *reinterpret_cast<const bf16x8*>(&sA[(wm * 32 + i * 16 + l16) * 4 + lk]);
#pragma unroll
        for (int j = 0; j < 4; j++)
            bfr[j] = *reinterpret_cast<const bf16x8*>(&sB[(wn * 64 + j * 16 + l16) * 4 + lk]);
#pragma unroll
        for (int i = 0; i < 2; i++)
#pragma unroll
            for (int j = 0; j < 4; j++)
                acc[i][j] = MF(af[i], bfr[j], acc[i][j]);
        __syncthreads();
    }

#pragma unroll
    for (int i = 0; i < 2; i++)
#pragma unroll
        for (int j = 0; j < 4; j++) {
            int col = nt * 128 + wn * 64 + j * 16 + l16;
            float add = u[col];
#pragma unroll
            for (int q = 0; q < 4; q++) {
                int row = mt * 64 + wm * 32 + i * 16 + lk * 4 + q;
                qp[(size_t)row * HH + col] = f2bf(acc[i][j][q] + add);
            }
        }
}

// ================= K5: flash attention (bf16 qp, online softmax) ============
__global__ __launch_bounds__(256) void attn2_kernel(
    const unsigned short* __restrict__ qp,  // [8192][768] bf16
    const float* __restrict__ res_all,      // [B*S][768] f32
    const int* __restrict__ starts,
    const int* __restrict__ lens,
    unsigned short* __restrict__ slotA)     // [8192][1536], writes cols 768..1535
{
    int bid = blockIdx.x;
    bid = (bid & 7) * 256 + (bid >> 3);              // 2048 = 8 x 256
    int gw = bid * 4 + (threadIdx.x >> 6);
    int lane = threadIdx.x & 63;
    int b = gw >> 8;
    int s0 = starts[gw];
    int sl = lens[gw];                               // 1..7, wave-uniform

    unsigned short* dst = slotA + (size_t)gw * 1536 + 768 + lane * 12;

    if (sl == 1) {                                   // word = first; xbar half = 0
        ushort4 z = {0, 0, 0, 0};
#pragma unroll
        for (int c = 0; c < 3; c++) *reinterpret_cast<ushort4*>(&dst[c * 4]) = z;
        return;
    }

    const unsigned short* qrow = qp + (size_t)gw * HH + lane * 12;
    float q[12];
#pragma unroll
    for (int c = 0; c < 3; c++) {
        ushort4 v = *reinterpret_cast<const ushort4*>(&qrow[c * 4]);
        q[c * 4 + 0] = bf2f(v.x); q[c * 4 + 1] = bf2f(v.y);
        q[c * 4 + 2] = bf2f(v.z); q[c * 4 + 3] = bf2f(v.w);
    }

    float m = -1e30f, ssum = 0.f;
    float acc[12];
#pragma unroll
    for (int i = 0; i < 12; i++) acc[i] = 0.f;

    for (int k = 0; k < LL; k++) {
        if (k > sl) break;                           // uniform branch
        int s = s0 + k; if (s > SS - 1) s = SS - 1;
        const float* xr = res_all + (size_t)(b * SS + s) * HH + lane * 12;
        float x[12];
        float partial = 0.f;
#pragma unroll
        for (int c = 0; c < 3; c++) {
            float4 v = *reinterpret_cast<const float4*>(&xr[c * 4]);
            x[c * 4 + 0] = v.x; x[c * 4 + 1] = v.y;
            x[c * 4 + 2] = v.z; x[c * 4 + 3] = v.w;
            partial += q[c * 4 + 0] * v.x + q[c * 4 + 1] * v.y
                     + q[c * 4 + 2] * v.z + q[c * 4 + 3] * v.w;
        }
#pragma unroll
        for (int off = 32; off > 0; off >>= 1) partial += __shfl_xor(partial, off);

        float mnew = (partial > m) ? partial : m;
        float scale = __expf(m - mnew);
        float e = __expf(partial - mnew);
        ssum = ssum * scale + e;
#pragma unroll
        for (int i = 0; i < 12; i++) acc[i] = acc[i] * scale + e * x[i];
        m = mnew;
    }

    float inv = 1.f / ssum;
#pragma unroll
    for (int c = 0; c < 3; c++) {
        ushort4 o;
        o.x = f2bf(acc[c * 4 + 0] * inv); o.y = f2bf(acc[c * 4 + 1] * inv);
        o.z = f2bf(acc[c * 4 + 2] * inv); o.w = f2bf(acc[c * 4 + 3] * inv);
        *reinterpret_cast<ushort4*>(&dst[c * 4]) = o;
    }
}

// ================= K6: slot-right GEMM + merge (32x128 tiles, 256 blocks) ===
__global__ __launch_bounds__(256) void gemm_slot_r(
    const uint4* __restrict__ A,    // slotA [8192][192]
    const uint4* __restrict__ Bm,   // Wcomb [128][192]
    const float* __restrict__ Cpart0,
    const float* __restrict__ bias, const float* __restrict__ wsbv,
    const int* __restrict__ lens,
    float* __restrict__ outsf)      // [8192][121]
{
    __shared__ uint4 sA[128];   // 32 rows
    __shared__ uint4 sB[512];   // 128 rows

    int mt = blockIdx.x;
    int t = threadIdx.x;
    int lane = t & 63, wave = t >> 6;
    int wm = wave >> 1, wn = wave & 1;
    int l16 = lane & 15, lk = lane >> 4;
    int srow = lane >> 2, schk = lane & 3;

    const uint4* Ag  = A + (size_t)(mt * 32 + wave * 16 + srow) * 192 + 96 + schk;
    const uint4* Bg0 = Bm + (size_t)(wave * 32 + srow) * 192 + 96 + schk;
    const uint4* Bg1 = Bg0 + (size_t)16 * 192;
    uint4* sB0 = &sB[wave * 128];
    uint4* sB1 = &sB[wave * 128 + 64];

    f32x4 acc[4] = {};

    for (int k0 = 0; k0 < 96; k0 += 4) {
        if (wave < 2) gload16(Ag + k0, &sA[wave * 64]);
        gload16(Bg0 + k0, sB0);
        gload16(Bg1 + k0, sB1);
        __syncthreads();
        bf16x8 af = *reinterpret_cast<const bf16x8*>(&sA[(wm * 16 + l16) * 4 + lk]);
        bf16x8 bfr[4];
#pragma unroll
        for (int j = 0; j < 4; j++)
            bfr[j] = *reinterpret_cast<const bf16x8*>(&sB[(wn * 64 + j * 16 + l16) * 4 + lk]);
#pragma unroll
        for (int j = 0; j < 4; j++)
            acc[j] = MF(af, bfr[j], acc[j]);
        __syncthreads();
    }

#pragma unroll
    for (int j = 0; j < 4; j++) {
        int col = wn * 64 + j * 16 + l16;
        if (col < NSLOT) {
            float bc = bias[col], wv = wsbv[col];
#pragma unroll
            for (int q = 0; q < 4; q++) {
                int row = mt * 32 + wm * 16 + lk * 4 + q;
                float v = acc[j][q] + Cpart0[(size_t)row * 128 + col]
                        + bc + ((lens[row] > 1) ? wv : 0.f);
                outsf[(size_t)row * NSLOT + col] = v;
            }
        }
    }
}

// ---------------- launch ----------------
extern "C" void kernel_launch(void* const* d_in, const int* in_sizes, int n_in,
                              void* d_out, int out_size, void* d_ws, size_t ws_size,
                              hipStream_t stream) {
    const float* res_all    = (const float*)d_in[0];
    const float* res        = (const float*)d_in[1];
    const int*   starts     = (const int*)d_in[2];
    const int*   lens       = (const int*)d_in[3];
    const float* Wsq_w      = (const float*)d_in[4];
    const float* Wsq_b      = (const float*)d_in[5];
    const float* Wsk_w      = (const float*)d_in[6];
    const float* Wsk_b      = (const float*)d_in[7];
    const float* Wsv_w      = (const float*)d_in[8];
    const float* Wsv_b      = (const float*)d_in[9];
    const float* lin_id_w   = (const float*)d_in[10];
    const float* lin_id_b   = (const float*)d_in[11];
    const float* lin_slot_w = (const float*)d_in[12];
    const float* lin_slot_b = (const float*)d_in[13];
    float* out = (float*)d_out;
    (void)Wsk_b;  // softmax-invariant (constant over k)

    char* ws = (char*)d_ws;
    unsigned short* slotA     = (unsigned short*)(ws + 0);          // 8192x1536 bf16
    unsigned short* qp        = (unsigned short*)(ws + 25165824);   // 8192x768 bf16
    unsigned short* WkT_hi    = (unsigned short*)(ws + 50331648);
    unsigned short* WkT_lo    = (unsigned short*)(ws + 51511296);
    unsigned short* WqT_hi    = (unsigned short*)(ws + 52690944);
    unsigned short* WqT_lo    = (unsigned short*)(ws + 53870592);
    unsigned short* WvT       = (unsigned short*)(ws + 55050240);
    unsigned short* Pb        = (unsigned short*)(ws + 56229888);   // 768^2 bf16
    unsigned short* Wcomb     = (unsigned short*)(ws + 57409536);   // 128x1536 bf16
    float*          u         = (float*)(ws + 57802752);            // 768
    float*          wsbv      = (float*)(ws + 57805824);            // 128
    float*          u_part    = (float*)(ws + 57806336);            // 12x768
    float*          wsbv_part = (float*)(ws + 57843200);            // 3x128
    float*          Ppart     = (float*)(ws + 57845760);            // 4x768x768 f32
    float*          WRpart    = (float*)(ws + 76720128);            // 4x128x768 f32
    float*          Cpart0    = (float*)(ws + 79865856);            // 8192x128 f32

    // K1: weight prep
    prep_w<<<816, 256, 0, stream>>>(
        Wsk_w, Wsq_w, Wsv_w, lin_slot_w, Wsq_b, Wsv_b,
        WkT_hi, WkT_lo, WqT_hi, WqT_lo, WvT, Wcomb,
        u_part, wsbv_part);

    // K2: weight GEMMs (ks4) + gather + res_id
    gemm_weights<<<2424, 256, 0, stream>>>(
        (const uint4*)WkT_hi, (const uint4*)WkT_lo,
        (const uint4*)WqT_hi, (const uint4*)WqT_lo,
        (const uint4*)WvT, (const uint4*)Wcomb,
        res_all, starts, res, lin_id_w, lin_id_b,
        Ppart, WRpart, slotA, out);

    // K3: reductions
    psum_kernel<<<676, 256, 0, stream>>>(
        (const float4*)Ppart, (ushort4*)Pb, (const float4*)WRpart, Wcomb,
        u_part, u, wsbv_part, wsbv);

    // K4': qp GEMM (bf16 out) + slot-left GEMM (overlapped in one launch)
    gemm_qp_sl<<<1024, 256, 0, stream>>>((const uint4*)slotA, (const uint4*)Pb,
                                         (const uint4*)Wcomb, u, qp, Cpart0);

    // K5: flash attention -> slotA right half
    attn2_kernel<<<2048, 256, 0, stream>>>(qp, res_all, starts, lens, slotA);

    // K6: slot-right GEMM + merge -> out
    gemm_slot_r<<<256, 256, 0, stream>>>((const uint4*)slotA, (const uint4*)Wcomb,
                                         Cpart0, lin_slot_b, wsbv, lens, out + 832);
}